// Round 2
// baseline (574.664 us; speedup 1.0000x reference)
//
#include <hip/hip_runtime.h>
#include <hip/hip_bf16.h>

#define BB   2
#define HH   256
#define WWD  256
#define CC   192
#define WSZ  8
#define TT   64
#define NHD  6
#define DHD  32
#define N3   576

typedef __attribute__((ext_vector_type(8))) short short8;
typedef __attribute__((ext_vector_type(4))) float f32x4;

__device__ inline short bf16_bits(float f) {
  __hip_bfloat16 h = __float2bfloat16(f);
  return __builtin_bit_cast(short, h);
}

// ---- kernel 0: pre-shuffle a row-major [K][ncols] weight into bf16 B-frags --
// frag gid = ct*384 + s*64 + lane; element j: B[k = s*32 + (lane>>4)*8 + j]
//                                             [col = ct*16 + (lane&15)]
__global__ __launch_bounds__(256) void lcam_wshuf(const float* __restrict__ src,
                                                  short* __restrict__ dst,
                                                  int ncols, int nfrag) {
  int gid = blockIdx.x * 256 + threadIdx.x;
  if (gid >= nfrag) return;
  int lane = gid & 63;
  int s = (gid >> 6) % 6;
  int ct = gid / 384;
  int col = ct * 16 + (lane & 15);
  int k0 = s * 32 + (lane >> 4) * 8;
  short8 v;
#pragma unroll
  for (int j = 0; j < 8; ++j)
    v[j] = bf16_bits(src[(size_t)(k0 + j) * ncols + col]);
  *(short8*)(dst + (size_t)gid * 8) = v;
}

// ---------------- kernel 1: spatial sum of x -> sums[b][c] ----------------
__global__ __launch_bounds__(256) void lcam_sum_x(const float* __restrict__ x,
                                                  float* __restrict__ sums) {
  int blk = blockIdx.x;            // 1024 blocks: 2 batches * 512 chunks of 128 px
  int b = blk >> 9;
  int chunk = blk & 511;
  const float* xp = x + ((size_t)b * 65536 + (size_t)chunk * 128) * CC;
  int t = threadIdx.x;
  if (t < CC) {
    float acc = 0.f;
    for (int p = 0; p < 128; ++p) acc += xp[(size_t)p * CC + t];
    atomicAdd(&sums[b * CC + t], acc);
  }
}

// ---------------- kernel 2: global token gt[b][c] ----------------
__global__ void lcam_gt(const float* __restrict__ sums,
                        const float* __restrict__ gt_w,
                        const float* __restrict__ gt_b,
                        float* __restrict__ gt) {
  int b = blockIdx.x;
  int co = threadIdx.x;            // 192 threads
  float acc = gt_b[co];
  const float inv = 1.f / 65536.f;
  for (int c = 0; c < CC; ++c)
    acc += sums[b * CC + c] * inv * gt_w[c * CC + co];
  gt[b * CC + co] = acc;
}

// ---- kernel 3: fully-fused window attention + projection, all-MFMA --------
// Register-accumulated projection (no 25.6KB os buffer), double-buffered
// ks/vt with ONE barrier per head, no-max softmax (scores Cauchy-Schwarz
// bounded by 0.177 since q,k are l2-normalized), deferred softmax
// denominator, fast exp/rcp/rsq. No min-waves clamp: LDS (39.1KB) binds
// occupancy; forcing <=128 VGPR would spill pacc[12].
__global__ __launch_bounds__(256) void lcam_attn(
    const float* __restrict__ x, const float* __restrict__ illu,
    const short* __restrict__ wf, const short* __restrict__ pwf,
    const float* __restrict__ qkv_b, const float* __restrict__ proj_b,
    const float* __restrict__ gt, float* __restrict__ out) {
  // bf16 LDS tiles; strides padded for 16B-aligned b128 reads, <=2-way banks
  __shared__ __align__(16) short qs[64 * 40];       // q (wave-local rows)
  __shared__ __align__(16) short ks[2][65 * 40];    // k, row64 = gt key (dbuf)
  __shared__ __align__(16) short vt[2][32 * 72];    // v^T [dim][key] (dbuf)
  __shared__ __align__(16) short ps[64 * 72];       // P unnormalized (wave-local rows)
  __shared__ __align__(16) short ot[64 * 40];       // O_h staging (wave-local rows)

  int w = blockIdx.x;          // 2048 windows
  int b  = w >> 10;
  int wy = (w >> 5) & 31;
  int wx = w & 31;
  int t  = threadIdx.x;
  int lane = t & 63;
  int rtile = t >> 6;             // wave = 16-row tile
  int m = lane & 15;
  int quad = lane >> 4;
  int key0 = rtile * 16 + quad * 4;   // first C-layout row this lane owns

  size_t base = ((size_t)(b * HH + wy * WSZ) * WWD + wx * WSZ) * CC;

  // ---- preload x A-frags (bf16), reused across all heads ----
  int apix = rtile * 16 + m;
  size_t arow = base + (size_t)((apix >> 3) * WWD + (apix & 7)) * CC + quad * 8;
  short8 afrag[6];
#pragma unroll
  for (int s = 0; s < 6; ++s) {
    const float* ap = x + arow + s * 32;
    float4 f0 = *(const float4*)(ap);
    float4 f1 = *(const float4*)(ap + 4);
    short8 v;
    v[0] = bf16_bits(f0.x); v[1] = bf16_bits(f0.y);
    v[2] = bf16_bits(f0.z); v[3] = bf16_bits(f0.w);
    v[4] = bf16_bits(f1.x); v[5] = bf16_bits(f1.y);
    v[6] = bf16_bits(f1.z); v[7] = bf16_bits(f1.w);
    afrag[s] = v;
  }
  const short8* wf8 = (const short8*)wf;
  const short8* pwf8 = (const short8*)pwf;

  // projection accumulators: 16 rows x 192 cols per wave, summed over heads
  f32x4 pacc[12];
#pragma unroll
  for (int ct = 0; ct < 12; ++ct) {
    f32x4 z = {0.f, 0.f, 0.f, 0.f};
    pacc[ct] = z;
  }

  for (int h = 0; h < NHD; ++h) {
    short* ksb = ks[h & 1];
    short* vtb = vt[h & 1];
    // early loads for this head (hide global latency under MFMA phases)
    float gv0 = gt[b * CC + h * 32 + m];
    float gv1 = gt[b * CC + h * 32 + 16 + m];
    float il0[4], il1[4];
#pragma unroll
    for (int r = 0; r < 4; ++r) {
      int key = key0 + r;
      const float* ip = illu + base + (size_t)((key >> 3) * WWD + (key & 7)) * CC + h * 32;
      il0[r] = ip[m];
      il1[r] = ip[16 + m];
    }
    // ---- Q: bias -> l2norm -> fold softmax scale -> qs (wave-local) ----
    {
      f32x4 a0 = {0.f,0.f,0.f,0.f}, a1 = {0.f,0.f,0.f,0.f};
      __builtin_amdgcn_s_setprio(1);
#pragma unroll
      for (int s = 0; s < 6; ++s)
        a0 = __builtin_amdgcn_mfma_f32_16x16x32_bf16(afrag[s], wf8[(2*h)*384 + s*64 + lane], a0, 0,0,0);
#pragma unroll
      for (int s = 0; s < 6; ++s)
        a1 = __builtin_amdgcn_mfma_f32_16x16x32_bf16(afrag[s], wf8[(2*h+1)*384 + s*64 + lane], a1, 0,0,0);
      __builtin_amdgcn_s_setprio(0);
      float b0 = qkv_b[h*32 + m], b1 = qkv_b[h*32 + 16 + m];
#pragma unroll
      for (int r = 0; r < 4; ++r) {
        float v0 = a0[r] + b0, v1 = a1[r] + b1;
        float ss = v0*v0 + v1*v1;
        ss += __shfl_xor(ss, 1); ss += __shfl_xor(ss, 2);
        ss += __shfl_xor(ss, 4); ss += __shfl_xor(ss, 8);
        float scl = 0.17677669529663688f * __builtin_amdgcn_rsqf(fmaxf(ss, 1e-24f));
        int row = key0 + r;
        qs[row*40 + m]      = bf16_bits(v0 * scl);
        qs[row*40 + 16 + m] = bf16_bits(v1 * scl);
      }
    }
    // ---- K: bias -> l2norm -> ksb ----
    {
      f32x4 a0 = {0.f,0.f,0.f,0.f}, a1 = {0.f,0.f,0.f,0.f};
      __builtin_amdgcn_s_setprio(1);
#pragma unroll
      for (int s = 0; s < 6; ++s)
        a0 = __builtin_amdgcn_mfma_f32_16x16x32_bf16(afrag[s], wf8[(12+2*h)*384 + s*64 + lane], a0, 0,0,0);
#pragma unroll
      for (int s = 0; s < 6; ++s)
        a1 = __builtin_amdgcn_mfma_f32_16x16x32_bf16(afrag[s], wf8[(13+2*h)*384 + s*64 + lane], a1, 0,0,0);
      __builtin_amdgcn_s_setprio(0);
      float b0 = qkv_b[192 + h*32 + m], b1 = qkv_b[192 + h*32 + 16 + m];
#pragma unroll
      for (int r = 0; r < 4; ++r) {
        float v0 = a0[r] + b0, v1 = a1[r] + b1;
        float ss = v0*v0 + v1*v1;
        ss += __shfl_xor(ss, 1); ss += __shfl_xor(ss, 2);
        ss += __shfl_xor(ss, 4); ss += __shfl_xor(ss, 8);
        float scl = __builtin_amdgcn_rsqf(fmaxf(ss, 1e-24f));
        int row = key0 + r;
        ksb[row*40 + m]      = bf16_bits(v0 * scl);
        ksb[row*40 + 16 + m] = bf16_bits(v1 * scl);
      }
    }
    // ---- V: bias -> *(1+sigmoid(illu)) -> vtb (transposed) ----
    {
      f32x4 a0 = {0.f,0.f,0.f,0.f}, a1 = {0.f,0.f,0.f,0.f};
      __builtin_amdgcn_s_setprio(1);
#pragma unroll
      for (int s = 0; s < 6; ++s)
        a0 = __builtin_amdgcn_mfma_f32_16x16x32_bf16(afrag[s], wf8[(24+2*h)*384 + s*64 + lane], a0, 0,0,0);
#pragma unroll
      for (int s = 0; s < 6; ++s)
        a1 = __builtin_amdgcn_mfma_f32_16x16x32_bf16(afrag[s], wf8[(25+2*h)*384 + s*64 + lane], a1, 0,0,0);
      __builtin_amdgcn_s_setprio(0);
      float b0 = qkv_b[384 + h*32 + m], b1 = qkv_b[384 + h*32 + 16 + m];
#pragma unroll
      for (int r = 0; r < 4; ++r) {
        int key = key0 + r;
        float s0 = __builtin_amdgcn_rcpf(1.f + __expf(-il0[r]));
        float s1 = __builtin_amdgcn_rcpf(1.f + __expf(-il1[r]));
        vtb[m*72 + key]        = bf16_bits((a0[r] + b0) * (1.f + s0));
        vtb[(16 + m)*72 + key] = bf16_bits((a1[r] + b1) * (1.f + s1));
      }
    }
    // global token = 65th key (raw gt, not normed/modulated)
    if (t < DHD) ksb[64*40 + t] = bf16_bits(gt[b*CC + h*DHD + t]);
    __syncthreads();   // ks/vt of this head visible; dbuf makes WAR safe
    // ---- QK^T (4 key tiles + broadcast gt-key tile) ----
    short8 qa = *(const short8*)(qs + (rtile*16 + m)*40 + quad*8);
    f32x4 sc[5];
#pragma unroll
    for (int ct = 0; ct < 4; ++ct) {
      short8 kb = *(const short8*)(ksb + (ct*16 + m)*40 + quad*8);
      f32x4 z = {0.f,0.f,0.f,0.f};
      sc[ct] = __builtin_amdgcn_mfma_f32_16x16x32_bf16(qa, kb, z, 0,0,0);
    }
    {
      short8 kb = *(const short8*)(ksb + 64*40 + quad*8);  // all lanes: gt row (bcast)
      f32x4 z = {0.f,0.f,0.f,0.f};
      sc[4] = __builtin_amdgcn_mfma_f32_16x16x32_bf16(qa, kb, z, 0,0,0);
    }
    // ---- softmax: scores bounded (|s|<=0.177), so no max-sub; denom deferred
    float p64v[4], invr[4];
#pragma unroll
    for (int r = 0; r < 4; ++r) {
      float e0 = __expf(sc[0][r]), e1 = __expf(sc[1][r]);
      float e2 = __expf(sc[2][r]), e3 = __expf(sc[3][r]);
      float e4 = (m == 0) ? __expf(sc[4][r]) : 0.f;   // gt key valid once per row
      int row = key0 + r;
      ps[row*72 + m]      = bf16_bits(e0);
      ps[row*72 + 16 + m] = bf16_bits(e1);
      ps[row*72 + 32 + m] = bf16_bits(e2);
      ps[row*72 + 48 + m] = bf16_bits(e3);
      float sum = e0 + e1 + e2 + e3 + e4;
      sum += __shfl_xor(sum, 1); sum += __shfl_xor(sum, 2);
      sum += __shfl_xor(sum, 4); sum += __shfl_xor(sum, 8);
      invr[r] = __builtin_amdgcn_rcpf(sum);
      p64v[r] = e4;
    }
    // ---- PV (keys 0..63) + rank-1 gt update, normalize at O ----
    f32x4 o0 = {0.f,0.f,0.f,0.f}, o1 = {0.f,0.f,0.f,0.f};
    __builtin_amdgcn_s_setprio(1);
#pragma unroll
    for (int kc = 0; kc < 2; ++kc) {
      short8 pa  = *(const short8*)(ps + (rtile*16 + m)*72 + kc*32 + quad*8);
      short8 vb0 = *(const short8*)(vtb + m*72        + kc*32 + quad*8);
      short8 vb1 = *(const short8*)(vtb + (16 + m)*72 + kc*32 + quad*8);
      o0 = __builtin_amdgcn_mfma_f32_16x16x32_bf16(pa, vb0, o0, 0,0,0);
      o1 = __builtin_amdgcn_mfma_f32_16x16x32_bf16(pa, vb1, o1, 0,0,0);
    }
    __builtin_amdgcn_s_setprio(0);
#pragma unroll
    for (int r = 0; r < 4; ++r) {
      float pr = __shfl(p64v[r], lane & 48);   // e4 from lane m==0 of quad
      int row = key0 + r;
      ot[row*40 + m]      = bf16_bits((o0[r] + pr * gv0) * invr[r]);
      ot[row*40 + 16 + m] = bf16_bits((o1[r] + pr * gv1) * invr[r]);
    }
    // ---- accumulate this head's projection slice (ot rows are wave-local) --
    short8 oa = *(const short8*)(ot + (rtile*16 + m)*40 + quad*8);
    __builtin_amdgcn_s_setprio(1);
#pragma unroll
    for (int ct = 0; ct < 12; ++ct)
      pacc[ct] = __builtin_amdgcn_mfma_f32_16x16x32_bf16(oa, pwf8[ct*384 + h*64 + lane], pacc[ct], 0,0,0);
    __builtin_amdgcn_s_setprio(0);
  }
  // ---- epilogue: bias + coalesced store (no barrier needed) ----
#pragma unroll
  for (int ct = 0; ct < 12; ++ct) {
    float bias = proj_b[ct*16 + m];
#pragma unroll
    for (int r = 0; r < 4; ++r) {
      int row = key0 + r;
      out[base + (size_t)((row >> 3) * WWD + (row & 7)) * CC + ct*16 + m] = pacc[ct][r] + bias;
    }
  }
}

// ------------- kernel 5: dwconv -> gelu -> dwconv, += into out -------------
__global__ __launch_bounds__(256) void lcam_pos(const float* __restrict__ x,
                                                const float* __restrict__ w1,
                                                const float* __restrict__ w2,
                                                float* __restrict__ out) {
  __shared__ __align__(16) float xt[20 * 20 * 16];
  __shared__ float t1[18 * 18 * 16];
  __shared__ float wl1[16 * 9], wl2[16 * 9];
  int blk = blockIdx.x;             // b(2) * ty(16) * tx(16) * cg(12)
  int cgI = blk % 12; int tmp = blk / 12;
  int tx = tmp % 16; tmp /= 16;
  int ty = tmp % 16; int b = tmp / 16;
  int c0 = cgI * 16;
  int y0 = ty * 16, x0 = tx * 16;
  int t = threadIdx.x;
  if (t < 144) { wl1[t] = w1[c0 * 9 + t]; wl2[t] = w2[c0 * 9 + t]; }
  // stage x halo 20x20x16 (zero outside image = SAME zero pad)
  for (int vi = t; vi < 1600; vi += 256) {
    int cc4 = vi & 3;
    int lin = vi >> 2;
    int xx = lin % 20, yy = lin / 20;
    int gy = y0 - 2 + yy, gx = x0 - 2 + xx;
    float4 v = {0.f, 0.f, 0.f, 0.f};
    if (gy >= 0 && gy < HH && gx >= 0 && gx < WWD)
      v = *(const float4*)(x + (((size_t)b * HH + gy) * WWD + gx) * CC + c0 + cc4 * 4);
    *(float4*)(xt + (yy * 20 + xx) * 16 + cc4 * 4) = v;
  }
  __syncthreads();
  // conv1 + exact gelu -> t1 halo 18x18x16; force 0 outside image (conv2 zero-pads)
  for (int idx = t; idx < 5184; idx += 256) {
    int cc = idx & 15;
    int xx = (idx >> 4) % 18;
    int yy = idx / 288;
    int gy = y0 - 1 + yy, gx = x0 - 1 + xx;
    float r = 0.f;
    if (gy >= 0 && gy < HH && gx >= 0 && gx < WWD) {
#pragma unroll
      for (int ky = 0; ky < 3; ++ky)
#pragma unroll
        for (int kx = 0; kx < 3; ++kx)
          r += xt[((yy + ky) * 20 + xx + kx) * 16 + cc] * wl1[cc * 9 + ky * 3 + kx];
      r = 0.5f * r * (1.f + erff(r * 0.70710678118654752f));
    }
    t1[(yy * 18 + xx) * 16 + cc] = r;
  }
  __syncthreads();
  // conv2 + add into out
  for (int idx = t; idx < 4096; idx += 256) {
    int cc = idx & 15;
    int xx = (idx >> 4) & 15;
    int yy = idx >> 8;
    float r = 0.f;
#pragma unroll
    for (int ky = 0; ky < 3; ++ky)
#pragma unroll
      for (int kx = 0; kx < 3; ++kx)
        r += t1[((yy + ky) * 18 + xx + kx) * 16 + cc] * wl2[cc * 9 + ky * 3 + kx];
    size_t o = (((size_t)b * HH + y0 + yy) * WWD + x0 + xx) * CC + c0 + cc;
    out[o] += r;
  }
}

extern "C" void kernel_launch(void* const* d_in, const int* in_sizes, int n_in,
                              void* d_out, int out_size, void* d_ws, size_t ws_size,
                              hipStream_t stream) {
  const float* x       = (const float*)d_in[0];
  const float* illu    = (const float*)d_in[1];
  const float* gt_w    = (const float*)d_in[2];
  const float* gt_b    = (const float*)d_in[3];
  const float* qkv_w   = (const float*)d_in[4];
  const float* qkv_b   = (const float*)d_in[5];
  const float* proj_w  = (const float*)d_in[6];
  const float* proj_b  = (const float*)d_in[7];
  const float* conv1_w = (const float*)d_in[8];
  const float* conv2_w = (const float*)d_in[9];
  float* out = (float*)d_out;

  short* wf   = (short*)d_ws;                          // 36*6*64*8 bf16 = 221184 B
  short* pwf  = (short*)((char*)d_ws + 221184);        // 12*6*64*8 bf16 =  73728 B
  float* sums = (float*)((char*)d_ws + 221184 + 73728);
  float* gt   = sums + BB * CC;

  hipMemsetAsync(sums, 0, BB * CC * sizeof(float), stream);
  lcam_wshuf<<<54, 256, 0, stream>>>(qkv_w, wf, N3, 36 * 6 * 64);
  lcam_wshuf<<<18, 256, 0, stream>>>(proj_w, pwf, CC, 12 * 6 * 64);
  lcam_sum_x<<<1024, 256, 0, stream>>>(x, sums);
  lcam_gt<<<BB, CC, 0, stream>>>(sums, gt_w, gt_b, gt);
  lcam_attn<<<2048, 256, 0, stream>>>(x, illu, wf, pwf, qkv_b, proj_b, gt, out);
  lcam_pos<<<6144, 256, 0, stream>>>(x, conv1_w, conv2_w, out);
}

// Round 4
// 501.855 us; speedup vs baseline: 1.1451x; 1.1451x over previous
//
#include <hip/hip_runtime.h>
#include <hip/hip_bf16.h>

#define BB   2
#define HH   256
#define WWD  256
#define CC   192
#define WSZ  8
#define TT   64
#define NHD  6
#define DHD  32
#define N3   576

typedef __attribute__((ext_vector_type(8))) short short8;
typedef __attribute__((ext_vector_type(4))) float f32x4;

__device__ inline short bf16_bits(float f) {
  __hip_bfloat16 h = __float2bfloat16(f);
  return __builtin_bit_cast(short, h);
}

// async 1KB stage: whole wave; per-lane 16B global src, linear LDS dst
__device__ inline void stage1k(const short* gsrc, short* ldst, int lane) {
  __builtin_amdgcn_global_load_lds(
      (const __attribute__((address_space(1))) void*)(gsrc + lane * 8),
      (__attribute__((address_space(3))) void*)ldst, 16, 0, 0);
}

// ---- kernel 0: pre-shuffle a row-major [K][ncols] weight into bf16 B-frags --
// frag gid = ct*384 + s*64 + lane; element j: B[k = s*32 + (lane>>4)*8 + j]
//                                             [col = ct*16 + (lane&15)]
// perm!=0: dst reordered s-major (head-major): frag -> (s*nct + ct)*64 + lane
__global__ __launch_bounds__(256) void lcam_wshuf(const float* __restrict__ src,
                                                  short* __restrict__ dst,
                                                  int ncols, int nfrag, int perm) {
  int gid = blockIdx.x * 256 + threadIdx.x;
  if (gid >= nfrag) return;
  int lane = gid & 63;
  int s = (gid >> 6) % 6;
  int ct = gid / 384;
  int col = ct * 16 + (lane & 15);
  int k0 = s * 32 + (lane >> 4) * 8;
  short8 v;
#pragma unroll
  for (int j = 0; j < 8; ++j)
    v[j] = bf16_bits(src[(size_t)(k0 + j) * ncols + col]);
  int didx = perm ? ((s * (ncols / 16) + ct) * 64 + lane) : gid;
  *(short8*)(dst + (size_t)didx * 8) = v;
}

// ---------------- kernel 1: spatial sum of x -> sums[b][c] ----------------
__global__ __launch_bounds__(256) void lcam_sum_x(const float* __restrict__ x,
                                                  float* __restrict__ sums) {
  int blk = blockIdx.x;            // 1024 blocks: 2 batches * 512 chunks of 128 px
  int b = blk >> 9;
  int chunk = blk & 511;
  const float* xp = x + ((size_t)b * 65536 + (size_t)chunk * 128) * CC;
  int t = threadIdx.x;
  if (t < CC) {
    float acc = 0.f;
    for (int p = 0; p < 128; ++p) acc += xp[(size_t)p * CC + t];
    atomicAdd(&sums[b * CC + t], acc);
  }
}

// ---------------- kernel 2: global token gt[b][c] ----------------
__global__ void lcam_gt(const float* __restrict__ sums,
                        const float* __restrict__ gt_w,
                        const float* __restrict__ gt_b,
                        float* __restrict__ gt) {
  int b = blockIdx.x;
  int co = threadIdx.x;            // 192 threads
  float acc = gt_b[co];
  const float inv = 1.f / 65536.f;
  for (int c = 0; c < CC; ++c)
    acc += sums[b * CC + c] * inv * gt_w[c * CC + co];
  gt[b * CC + co] = acc;
}

// ---- kernel 3: fused window attention + projection, LDS-staged weights ----
// Per head, the 48KB weight slice (QKV 36KB + proj 12KB) is staged into LDS
// ONCE per block via global_load_lds (prefetched a phase ahead, overlapped
// with MFMA), instead of each of 4 waves pulling its own copy from L2
// (4x cut of the per-CU global-port traffic that bound rounds 0-2).
__global__ __launch_bounds__(256) void lcam_attn(
    const float* __restrict__ x, const float* __restrict__ illu,
    const short* __restrict__ wf, const short* __restrict__ pwf,
    const float* __restrict__ qkv_b, const float* __restrict__ proj_b,
    const float* __restrict__ gt, float* __restrict__ out) {
  __shared__ __align__(16) short wq[3 * 768 * 8];  // QKV B-frags head h: [r][ct'][s][lane] 36KB
  __shared__ __align__(16) short wp[768 * 8];      // proj B-frags head h: [ct][lane] 12KB
  __shared__ __align__(16) short ks[65 * 40];      // k rows, row64 = gt key
  __shared__ __align__(16) short vt[32 * 72];      // v^T [dim][key]
  __shared__ __align__(16) short qs[64 * 40];      // q (wave-private rows); reused as O_h
  __shared__ __align__(16) short ps[64 * 72];      // P unnormalized (wave-private rows)

  int w = blockIdx.x;          // 2048 windows
  int b  = w >> 10;
  int wy = (w >> 5) & 31;
  int wx = w & 31;
  int t  = threadIdx.x;
  int lane = t & 63;
  int rtile = t >> 6;             // wave = 16-row tile
  int m = lane & 15;
  int quad = lane >> 4;
  int key0 = rtile * 16 + quad * 4;   // first C-layout row this lane owns

  size_t base = ((size_t)(b * HH + wy * WSZ) * WWD + wx * WSZ) * CC;

  // ---- prologue: stage wq[0] (36 x 1KB chunks, 9 per wave) ----
#pragma unroll
  for (int u = 0; u < 9; ++u) {
    int j = rtile * 9 + u;
    int rr = j / 12, ii = j % 12;
    stage1k(wf + (rr * 12) * 3072 + ii * 512, wq + rr * 6144 + ii * 512, lane);
  }

  // ---- preload x A-frags (bf16), reused across all heads ----
  int apix = rtile * 16 + m;
  size_t arow = base + (size_t)((apix >> 3) * WWD + (apix & 7)) * CC + quad * 8;
  short8 afrag[6];
#pragma unroll
  for (int s = 0; s < 6; ++s) {
    const float* ap = x + arow + s * 32;
    float4 f0 = *(const float4*)(ap);
    float4 f1 = *(const float4*)(ap + 4);
    short8 v;
    v[0] = bf16_bits(f0.x); v[1] = bf16_bits(f0.y);
    v[2] = bf16_bits(f0.z); v[3] = bf16_bits(f0.w);
    v[4] = bf16_bits(f1.x); v[5] = bf16_bits(f1.y);
    v[6] = bf16_bits(f1.z); v[7] = bf16_bits(f1.w);
    afrag[s] = v;
  }
  const short8* wq8 = (const short8*)wq;
  const short8* wp8 = (const short8*)wp;

  // projection accumulators: 16 rows x 192 cols per wave, summed over heads
  f32x4 pacc[12];
#pragma unroll
  for (int ct = 0; ct < 12; ++ct) {
    f32x4 z = {0.f, 0.f, 0.f, 0.f};
    pacc[ct] = z;
  }

  __syncthreads();   // wq[0] staged (barrier drains vmcnt)

  for (int h = 0; h < NHD; ++h) {
    // ======================= phase A: QKV from wq[h] =======================
    // stage wp[h] (12 x 1KB, 3 per wave) - consumed in phase B after barrier
#pragma unroll
    for (int u = 0; u < 3; ++u) {
      int ii = rtile * 3 + u;
      stage1k(pwf + h * 6144 + ii * 512, wp + ii * 512, lane);
    }
    // early loads for this head (hide global latency under MFMA phases)
    float gv0 = gt[b * CC + h * 32 + m];
    float gv1 = gt[b * CC + h * 32 + 16 + m];
    float il0[4], il1[4];
#pragma unroll
    for (int r = 0; r < 4; ++r) {
      int key = key0 + r;
      const float* ip = illu + base + (size_t)((key >> 3) * WWD + (key & 7)) * CC + h * 32;
      il0[r] = ip[m];
      il1[r] = ip[16 + m];
    }
    // ---- Q: bias -> l2norm -> fold softmax scale -> qs (wave-private) ----
    {
      f32x4 a0 = {0.f,0.f,0.f,0.f}, a1 = {0.f,0.f,0.f,0.f};
      __builtin_amdgcn_s_setprio(1);
#pragma unroll
      for (int s = 0; s < 6; ++s)
        a0 = __builtin_amdgcn_mfma_f32_16x16x32_bf16(afrag[s], wq8[s*64 + lane], a0, 0,0,0);
#pragma unroll
      for (int s = 0; s < 6; ++s)
        a1 = __builtin_amdgcn_mfma_f32_16x16x32_bf16(afrag[s], wq8[384 + s*64 + lane], a1, 0,0,0);
      __builtin_amdgcn_s_setprio(0);
      float b0 = qkv_b[h*32 + m], b1 = qkv_b[h*32 + 16 + m];
#pragma unroll
      for (int r = 0; r < 4; ++r) {
        float v0 = a0[r] + b0, v1 = a1[r] + b1;
        float ss = v0*v0 + v1*v1;
        ss += __shfl_xor(ss, 1); ss += __shfl_xor(ss, 2);
        ss += __shfl_xor(ss, 4); ss += __shfl_xor(ss, 8);
        float scl = 0.17677669529663688f * __builtin_amdgcn_rsqf(fmaxf(ss, 1e-24f));
        int row = key0 + r;
        qs[row*40 + m]      = bf16_bits(v0 * scl);
        qs[row*40 + 16 + m] = bf16_bits(v1 * scl);
      }
    }
    // ---- K: bias -> l2norm -> ks ----
    {
      f32x4 a0 = {0.f,0.f,0.f,0.f}, a1 = {0.f,0.f,0.f,0.f};
      __builtin_amdgcn_s_setprio(1);
#pragma unroll
      for (int s = 0; s < 6; ++s)
        a0 = __builtin_amdgcn_mfma_f32_16x16x32_bf16(afrag[s], wq8[768 + s*64 + lane], a0, 0,0,0);
#pragma unroll
      for (int s = 0; s < 6; ++s)
        a1 = __builtin_amdgcn_mfma_f32_16x16x32_bf16(afrag[s], wq8[1152 + s*64 + lane], a1, 0,0,0);
      __builtin_amdgcn_s_setprio(0);
      float b0 = qkv_b[192 + h*32 + m], b1 = qkv_b[192 + h*32 + 16 + m];
#pragma unroll
      for (int r = 0; r < 4; ++r) {
        float v0 = a0[r] + b0, v1 = a1[r] + b1;
        float ss = v0*v0 + v1*v1;
        ss += __shfl_xor(ss, 1); ss += __shfl_xor(ss, 2);
        ss += __shfl_xor(ss, 4); ss += __shfl_xor(ss, 8);
        float scl = __builtin_amdgcn_rsqf(fmaxf(ss, 1e-24f));
        int row = key0 + r;
        ks[row*40 + m]      = bf16_bits(v0 * scl);
        ks[row*40 + 16 + m] = bf16_bits(v1 * scl);
      }
    }
    // ---- V: bias -> *(1+sigmoid(illu)) -> vt (transposed) ----
    {
      f32x4 a0 = {0.f,0.f,0.f,0.f}, a1 = {0.f,0.f,0.f,0.f};
      __builtin_amdgcn_s_setprio(1);
#pragma unroll
      for (int s = 0; s < 6; ++s)
        a0 = __builtin_amdgcn_mfma_f32_16x16x32_bf16(afrag[s], wq8[1536 + s*64 + lane], a0, 0,0,0);
#pragma unroll
      for (int s = 0; s < 6; ++s)
        a1 = __builtin_amdgcn_mfma_f32_16x16x32_bf16(afrag[s], wq8[1920 + s*64 + lane], a1, 0,0,0);
      __builtin_amdgcn_s_setprio(0);
      float b0 = qkv_b[384 + h*32 + m], b1 = qkv_b[384 + h*32 + 16 + m];
#pragma unroll
      for (int r = 0; r < 4; ++r) {
        int key = key0 + r;
        float s0 = __builtin_amdgcn_rcpf(1.f + __expf(-il0[r]));
        float s1 = __builtin_amdgcn_rcpf(1.f + __expf(-il1[r]));
        vt[m*72 + key]        = bf16_bits((a0[r] + b0) * (1.f + s0));
        vt[(16 + m)*72 + key] = bf16_bits((a1[r] + b1) * (1.f + s1));
      }
    }
    // global token = 65th key (raw gt, not normed/modulated)
    if (t < DHD) ks[64*40 + t] = bf16_bits(gt[b*CC + h*DHD + t]);
    __syncthreads();   // BARRIER1: k/v/gt visible; wp[h] staged (vmcnt drained)
    // ======================= phase B: attention + proj =====================
    short8 qa = *(const short8*)(qs + (rtile*16 + m)*40 + quad*8);
    f32x4 sc[5];
#pragma unroll
    for (int ct = 0; ct < 4; ++ct) {
      short8 kb = *(const short8*)(ks + (ct*16 + m)*40 + quad*8);
      f32x4 z = {0.f,0.f,0.f,0.f};
      sc[ct] = __builtin_amdgcn_mfma_f32_16x16x32_bf16(qa, kb, z, 0,0,0);
    }
    {
      short8 kb = *(const short8*)(ks + 64*40 + quad*8);  // all lanes: gt row (bcast)
      f32x4 z = {0.f,0.f,0.f,0.f};
      sc[4] = __builtin_amdgcn_mfma_f32_16x16x32_bf16(qa, kb, z, 0,0,0);
    }
    // stage wq[h+1] (36 x 1KB, 9 per wave) - consumed after end-of-iter barrier
    if (h < NHD - 1) {
#pragma unroll
      for (int u = 0; u < 9; ++u) {
        int j = rtile * 9 + u;
        int rr = j / 12, ii = j % 12;
        stage1k(wf + (rr * 12 + 2 * (h + 1)) * 3072 + ii * 512,
                wq + rr * 6144 + ii * 512, lane);
      }
    }
    // ---- softmax: scores bounded (|s|<=0.177), no max-sub; denom deferred
    float p64v[4], invr[4];
#pragma unroll
    for (int r = 0; r < 4; ++r) {
      float e0 = __expf(sc[0][r]), e1 = __expf(sc[1][r]);
      float e2 = __expf(sc[2][r]), e3 = __expf(sc[3][r]);
      float e4 = (m == 0) ? __expf(sc[4][r]) : 0.f;   // gt key valid once per row
      int row = key0 + r;
      ps[row*72 + m]      = bf16_bits(e0);
      ps[row*72 + 16 + m] = bf16_bits(e1);
      ps[row*72 + 32 + m] = bf16_bits(e2);
      ps[row*72 + 48 + m] = bf16_bits(e3);
      float sum = e0 + e1 + e2 + e3 + e4;
      sum += __shfl_xor(sum, 1); sum += __shfl_xor(sum, 2);
      sum += __shfl_xor(sum, 4); sum += __shfl_xor(sum, 8);
      invr[r] = __builtin_amdgcn_rcpf(sum);
      p64v[r] = e4;
    }
    // ---- PV (keys 0..63) + rank-1 gt update, normalize at O ----
    f32x4 o0 = {0.f,0.f,0.f,0.f}, o1 = {0.f,0.f,0.f,0.f};
    __builtin_amdgcn_s_setprio(1);
#pragma unroll
    for (int kc = 0; kc < 2; ++kc) {
      short8 pa  = *(const short8*)(ps + (rtile*16 + m)*72 + kc*32 + quad*8);
      short8 vb0 = *(const short8*)(vt + m*72        + kc*32 + quad*8);
      short8 vb1 = *(const short8*)(vt + (16 + m)*72 + kc*32 + quad*8);
      o0 = __builtin_amdgcn_mfma_f32_16x16x32_bf16(pa, vb0, o0, 0,0,0);
      o1 = __builtin_amdgcn_mfma_f32_16x16x32_bf16(pa, vb1, o1, 0,0,0);
    }
    __builtin_amdgcn_s_setprio(0);
    // O_h staged into qs (wave-private rows; qa reads are done above)
#pragma unroll
    for (int r = 0; r < 4; ++r) {
      float pr = __shfl(p64v[r], lane & 48);   // e4 from lane m==0 of quad
      int row = key0 + r;
      qs[row*40 + m]      = bf16_bits((o0[r] + pr * gv0) * invr[r]);
      qs[row*40 + 16 + m] = bf16_bits((o1[r] + pr * gv1) * invr[r]);
    }
    // ---- accumulate this head's projection slice from wp[h] ----
    short8 oa = *(const short8*)(qs + (rtile*16 + m)*40 + quad*8);
    __builtin_amdgcn_s_setprio(1);
#pragma unroll
    for (int ct = 0; ct < 12; ++ct)
      pacc[ct] = __builtin_amdgcn_mfma_f32_16x16x32_bf16(oa, wp8[ct*64 + lane], pacc[ct], 0,0,0);
    __builtin_amdgcn_s_setprio(0);
    __syncthreads();   // BARRIER2: phase-B reads done; wq[h+1] staged
  }
  // ---- epilogue: bias + coalesced store ----
#pragma unroll
  for (int ct = 0; ct < 12; ++ct) {
    float bias = proj_b[ct*16 + m];
#pragma unroll
    for (int r = 0; r < 4; ++r) {
      int row = key0 + r;
      out[base + (size_t)((row >> 3) * WWD + (row & 7)) * CC + ct*16 + m] = pacc[ct][r] + bias;
    }
  }
}

// ------------- kernel 5: dwconv -> gelu -> dwconv, += into out -------------
__global__ __launch_bounds__(256) void lcam_pos(const float* __restrict__ x,
                                                const float* __restrict__ w1,
                                                const float* __restrict__ w2,
                                                float* __restrict__ out) {
  __shared__ __align__(16) float xt[20 * 20 * 16];
  __shared__ float t1[18 * 18 * 16];
  __shared__ float wl1[16 * 9], wl2[16 * 9];
  int blk = blockIdx.x;             // b(2) * ty(16) * tx(16) * cg(12)
  int cgI = blk % 12; int tmp = blk / 12;
  int tx = tmp % 16; tmp /= 16;
  int ty = tmp % 16; int b = tmp / 16;
  int c0 = cgI * 16;
  int y0 = ty * 16, x0 = tx * 16;
  int t = threadIdx.x;
  if (t < 144) { wl1[t] = w1[c0 * 9 + t]; wl2[t] = w2[c0 * 9 + t]; }
  // stage x halo 20x20x16 (zero outside image = SAME zero pad)
  for (int vi = t; vi < 1600; vi += 256) {
    int cc4 = vi & 3;
    int lin = vi >> 2;
    int xx = lin % 20, yy = lin / 20;
    int gy = y0 - 2 + yy, gx = x0 - 2 + xx;
    float4 v = {0.f, 0.f, 0.f, 0.f};
    if (gy >= 0 && gy < HH && gx >= 0 && gx < WWD)
      v = *(const float4*)(x + (((size_t)b * HH + gy) * WWD + gx) * CC + c0 + cc4 * 4);
    *(float4*)(xt + (yy * 20 + xx) * 16 + cc4 * 4) = v;
  }
  __syncthreads();
  // conv1 + exact gelu -> t1 halo 18x18x16; force 0 outside image (conv2 zero-pads)
  for (int idx = t; idx < 5184; idx += 256) {
    int cc = idx & 15;
    int xx = (idx >> 4) % 18;
    int yy = idx / 288;
    int gy = y0 - 1 + yy, gx = x0 - 1 + xx;
    float r = 0.f;
    if (gy >= 0 && gy < HH && gx >= 0 && gx < WWD) {
#pragma unroll
      for (int ky = 0; ky < 3; ++ky)
#pragma unroll
        for (int kx = 0; kx < 3; ++kx)
          r += xt[((yy + ky) * 20 + xx + kx) * 16 + cc] * wl1[cc * 9 + ky * 3 + kx];
      r = 0.5f * r * (1.f + erff(r * 0.70710678118654752f));
    }
    t1[(yy * 18 + xx) * 16 + cc] = r;
  }
  __syncthreads();
  // conv2 + add into out
  for (int idx = t; idx < 4096; idx += 256) {
    int cc = idx & 15;
    int xx = (idx >> 4) & 15;
    int yy = idx >> 8;
    float r = 0.f;
#pragma unroll
    for (int ky = 0; ky < 3; ++ky)
#pragma unroll
      for (int kx = 0; kx < 3; ++kx)
        r += t1[((yy + ky) * 18 + xx + kx) * 16 + cc] * wl2[cc * 9 + ky * 3 + kx];
    size_t o = (((size_t)b * HH + y0 + yy) * WWD + x0 + xx) * CC + c0 + cc;
    out[o] += r;
  }
}

extern "C" void kernel_launch(void* const* d_in, const int* in_sizes, int n_in,
                              void* d_out, int out_size, void* d_ws, size_t ws_size,
                              hipStream_t stream) {
  const float* x       = (const float*)d_in[0];
  const float* illu    = (const float*)d_in[1];
  const float* gt_w    = (const float*)d_in[2];
  const float* gt_b    = (const float*)d_in[3];
  const float* qkv_w   = (const float*)d_in[4];
  const float* qkv_b   = (const float*)d_in[5];
  const float* proj_w  = (const float*)d_in[6];
  const float* proj_b  = (const float*)d_in[7];
  const float* conv1_w = (const float*)d_in[8];
  const float* conv2_w = (const float*)d_in[9];
  float* out = (float*)d_out;

  short* wf   = (short*)d_ws;                          // 36*6*64*8 bf16 = 221184 B
  short* pwf  = (short*)((char*)d_ws + 221184);        // 12*6*64*8 bf16 =  73728 B (head-major)
  float* sums = (float*)((char*)d_ws + 221184 + 73728);
  float* gt   = sums + BB * CC;

  hipMemsetAsync(sums, 0, BB * CC * sizeof(float), stream);
  lcam_wshuf<<<54, 256, 0, stream>>>(qkv_w, wf, N3, 36 * 6 * 64, 0);
  lcam_wshuf<<<18, 256, 0, stream>>>(proj_w, pwf, CC, 12 * 6 * 64, 1);
  lcam_sum_x<<<1024, 256, 0, stream>>>(x, sums);
  lcam_gt<<<BB, CC, 0, stream>>>(sums, gt_w, gt_b, gt);
  lcam_attn<<<2048, 256, 0, stream>>>(x, illu, wf, pwf, qkv_b, proj_b, gt, out);
  lcam_pos<<<6144, 256, 0, stream>>>(x, conv1_w, conv2_w, out);
}